// Round 2
// baseline (190.209 us; speedup 1.0000x reference)
//
#include <hip/hip_runtime.h>
#include <hip/hip_bf16.h>
#include <math.h>

// Problem constants (fixed by setup_inputs)
#define BATCH 8
#define SEQ   4096
#define DIM   512        // D
#define FDIM  4          // F
#define M_TOTAL (BATCH*SEQ)   // 32768 positions
#define K_TOTAL (2*DIM)       // 1024 (cat = [ctx; q])
#define N_TOTAL DIM           // 512

typedef __bf16 bf16x8 __attribute__((ext_vector_type(8)));
typedef float  f32x4  __attribute__((ext_vector_type(4)));

__device__ __forceinline__ void gload_lds16(const void* g, void* l) {
    __builtin_amdgcn_global_load_lds(
        (__attribute__((address_space(1))) void*)(void*)g,
        (__attribute__((address_space(3))) void*)l,
        16, 0, 0);
}

// ---------------------------------------------------------------------------
// Kernel 1: per-position attention -> cat (bf16) and gate (f32)
// One block (256 threads) per position.
// ---------------------------------------------------------------------------
__global__ __launch_bounds__(256)
void pre_kernel(const float* __restrict__ inputs,
                const float* __restrict__ values,
                const float* __restrict__ w_score,
                const float* __restrict__ b_score,
                const int*   __restrict__ n_ptr,
                __hip_bfloat16* __restrict__ cat,
                float* __restrict__ gate)
{
    __shared__ __align__(16) float qs[DIM];        // 2 KB
    __shared__ __align__(16) float ms[FDIM*DIM];   // 8 KB
    __shared__ float sc[FDIM];
    __shared__ float red[4];

    const int tid  = threadIdx.x;
    const int p    = blockIdx.x;
    const int lane = tid & 63;
    const int wv   = tid >> 6;      // 4 waves

    const float* qg = inputs + (size_t)p * DIM;
    const float* vg = values + (size_t)p * (FDIM*DIM);

    // stage q and mem in LDS (coalesced float4)
    if (tid < DIM/4) ((float4*)qs)[tid] = ((const float4*)qg)[tid];
    ((float4*)ms)[tid]       = ((const float4*)vg)[tid];
    ((float4*)ms)[tid + 256] = ((const float4*)vg)[tid + 256];
    __syncthreads();

    // wave w computes score[w] = dot(q, mem[w]); also gate partials
    const int nv = *n_ptr;
    {
        float s = 0.f;
        const float* mw = ms + wv * DIM;
        #pragma unroll
        for (int j = 0; j < 8; ++j) {
            int d = lane * 8 + j;
            s += mw[d] * qs[d];
        }
        #pragma unroll
        for (int off = 32; off > 0; off >>= 1) s += __shfl_down(s, off, 64);
        if (lane == 0) sc[wv] = (wv < nv) ? s : -1e9f;
    }
    // gate partial (each thread covers d=tid and d=tid+256)
    {
        float g = qs[tid] * w_score[tid] + qs[tid + 256] * w_score[tid + 256];
        #pragma unroll
        for (int off = 32; off > 0; off >>= 1) g += __shfl_down(g, off, 64);
        if (lane == 0) red[wv] = g;
    }
    __syncthreads();

    // softmax over the F scores (redundant per thread, cheap)
    float s0 = sc[0], s1 = sc[1], s2 = sc[2], s3 = sc[3];
    float mx = fmaxf(fmaxf(s0, s1), fmaxf(s2, s3));
    float e0 = expf(s0 - mx), e1 = expf(s1 - mx), e2 = expf(s2 - mx), e3 = expf(s3 - mx);
    float inv = 1.f / (e0 + e1 + e2 + e3);
    float a0 = e0 * inv, a1 = e1 * inv, a2 = e2 * inv, a3 = e3 * inv;

    // ctx + cat write (bf16)
    __hip_bfloat16* cp = cat + (size_t)p * K_TOTAL;
    #pragma unroll
    for (int rep = 0; rep < 2; ++rep) {
        int d = tid + rep * 256;
        float c = a0 * ms[d] + a1 * ms[DIM + d] + a2 * ms[2*DIM + d] + a3 * ms[3*DIM + d];
        cp[d]       = __float2bfloat16(c);
        cp[DIM + d] = __float2bfloat16(qs[d]);
    }

    if (tid == 0) {
        float t = red[0] + red[1] + red[2] + red[3] + b_score[0];
        gate[p] = 1.f / (1.f + expf(-t));
    }
}

// ---------------------------------------------------------------------------
// Kernel 2: W_out [1024,512] f32 -> Wt [512,1024] bf16 (transpose+convert)
// ---------------------------------------------------------------------------
__global__ __launch_bounds__(256)
void wconv(const float* __restrict__ W, __hip_bfloat16* __restrict__ Wt)
{
    int idx = blockIdx.x * 256 + threadIdx.x;   // 0 .. 1024*512-1
    int k  = idx >> 9;        // row of W (0..1023)
    int nn = idx & 511;       // col of W (0..511)
    Wt[(size_t)nn * K_TOTAL + k] = __float2bfloat16(W[idx]);
}

// ---------------------------------------------------------------------------
// Kernel 3: out = tanh(cat @ W_out) * gate + inputs
// bf16 MFMA GEMM, BM=BN=128, BK=32, 4 waves (2x2), 4x4 16x16 frags per wave.
// A = cat [M,1024] row-major bf16; Bt = Wt [N,1024] row-major bf16 (B^T).
// ---------------------------------------------------------------------------
__global__ __launch_bounds__(256)
void gemm_ep(const __hip_bfloat16* __restrict__ A,
             const __hip_bfloat16* __restrict__ Bt,
             const float* __restrict__ gate,
             const float* __restrict__ inputs,
             float* __restrict__ out)
{
    __shared__ __align__(16) __hip_bfloat16 As[128 * 32];  // 8 KB
    __shared__ __align__(16) __hip_bfloat16 Bs[128 * 32];  // 8 KB

    const int tid  = threadIdx.x;
    const int bm   = blockIdx.x;
    const int bn   = blockIdx.y;
    const int wid  = tid >> 6;
    const int lane = tid & 63;
    const int wr   = wid >> 1;       // wave row 0..1
    const int wc   = wid & 1;        // wave col 0..1
    const int la   = lane & 15;
    const int lb   = lane >> 4;

    const int K = K_TOTAL;
    const __hip_bfloat16* Ag = A  + (size_t)(bm * 128) * K;
    const __hip_bfloat16* Bg = Bt + (size_t)(bn * 128) * K;

    const int sr = tid >> 2;          // staging row 0..63
    const int sk = (tid & 3) * 8;     // staging k element offset (16B chunks)

    f32x4 acc[4][4] = {};

    for (int kt = 0; kt < K; kt += 32) {
        __syncthreads();
        gload_lds16(Ag + (size_t)sr * K + kt + sk,        As + tid * 8);
        gload_lds16(Ag + (size_t)(sr + 64) * K + kt + sk, As + 2048 + tid * 8);
        gload_lds16(Bg + (size_t)sr * K + kt + sk,        Bs + tid * 8);
        gload_lds16(Bg + (size_t)(sr + 64) * K + kt + sk, Bs + 2048 + tid * 8);
        __syncthreads();   // compiler emits vmcnt(0) drain before barrier

        bf16x8 af[4], bfv[4];
        #pragma unroll
        for (int i = 0; i < 4; ++i)
            af[i] = *reinterpret_cast<const bf16x8*>(As + (wr*64 + i*16 + la) * 32 + lb * 8);
        #pragma unroll
        for (int j = 0; j < 4; ++j)
            bfv[j] = *reinterpret_cast<const bf16x8*>(Bs + (wc*64 + j*16 + la) * 32 + lb * 8);

        #pragma unroll
        for (int i = 0; i < 4; ++i)
            #pragma unroll
            for (int j = 0; j < 4; ++j)
                acc[i][j] = __builtin_amdgcn_mfma_f32_16x16x32_bf16(af[i], bfv[j], acc[i][j], 0, 0, 0);
    }

    // Epilogue: C/D mapping col = lane&15, row = (lane>>4)*4 + reg  [m89/m91]
    const int row0 = bm * 128 + wr * 64;
    const int col0 = bn * 128 + wc * 64;
    #pragma unroll
    for (int i = 0; i < 4; ++i) {
        #pragma unroll
        for (int j = 0; j < 4; ++j) {
            const int col = col0 + j * 16 + la;
            const int rb  = row0 + i * 16 + lb * 4;
            #pragma unroll
            for (int r = 0; r < 4; ++r) {
                const int row = rb + r;
                float v = tanhf(acc[i][j][r]) * gate[row] + inputs[(size_t)row * DIM + col];
                out[(size_t)row * DIM + col] = v;
            }
        }
    }
}

// ---------------------------------------------------------------------------
extern "C" void kernel_launch(void* const* d_in, const int* in_sizes, int n_in,
                              void* d_out, int out_size, void* d_ws, size_t ws_size,
                              hipStream_t stream) {
    const float* inputs  = (const float*)d_in[0];
    const float* values  = (const float*)d_in[1];
    const float* W_out   = (const float*)d_in[2];
    const float* w_score = (const float*)d_in[3];
    const float* b_score = (const float*)d_in[4];
    const int*   n_ptr   = (const int*)d_in[5];
    float* out = (float*)d_out;

    char* ws = (char*)d_ws;
    __hip_bfloat16* cat  = (__hip_bfloat16*)ws;                                   // 64 MiB
    float*          gate = (float*)(ws + (size_t)M_TOTAL * K_TOTAL * 2);          // 128 KiB
    __hip_bfloat16* Wt   = (__hip_bfloat16*)(ws + (size_t)M_TOTAL * K_TOTAL * 2
                                                + (size_t)M_TOTAL * 4);           // 1 MiB

    pre_kernel<<<M_TOTAL, 256, 0, stream>>>(inputs, values, w_score, b_score, n_ptr, cat, gate);
    wconv<<<(K_TOTAL * N_TOTAL) / 256, 256, 0, stream>>>(W_out, Wt);
    dim3 g3(M_TOTAL / 128, N_TOTAL / 128);
    gemm_ep<<<g3, 256, 0, stream>>>(cat, Wt, gate, inputs, out);
}

// Round 3
// 135.287 us; speedup vs baseline: 1.4060x; 1.4060x over previous
//
#include <hip/hip_runtime.h>
#include <hip/hip_bf16.h>
#include <math.h>

// Problem constants (fixed by setup_inputs)
#define BATCH 8
#define SEQ   4096
#define DIM   512        // D
#define FDIM  4          // F
#define M_TOTAL (BATCH*SEQ)   // 32768 positions
#define K_TOTAL (2*DIM)       // 1024 (cat = [ctx; q])
#define N_TOTAL DIM           // 512

#define PRE_BLOCKS (M_TOTAL/4)          // 8192 blocks, 4 positions (waves) each
#define WCONV_BLOCKS ((K_TOTAL/64)*(N_TOTAL/64))  // 16*8 = 128 tiles

typedef __bf16 bf16x8 __attribute__((ext_vector_type(8)));
typedef float  f32x4  __attribute__((ext_vector_type(4)));

__device__ __forceinline__ void gload_lds16(const void* g, void* l) {
    __builtin_amdgcn_global_load_lds(
        (__attribute__((address_space(1))) void*)(void*)g,
        (__attribute__((address_space(3))) void*)l,
        16, 0, 0);
}

__device__ __forceinline__ float dot4(float4 a, float4 b) {
    return a.x*b.x + a.y*b.y + a.z*b.z + a.w*b.w;
}

__device__ __forceinline__ void store_bf4(__hip_bfloat16* dst, float4 v) {
    __hip_bfloat16 t[4];
    t[0] = __float2bfloat16(v.x); t[1] = __float2bfloat16(v.y);
    t[2] = __float2bfloat16(v.z); t[3] = __float2bfloat16(v.w);
    *reinterpret_cast<uint2*>(dst) = *reinterpret_cast<const uint2*>(t);
}

__device__ __forceinline__ float fast_tanh(float x) {
    // tanh(x) = 1 - 2/(e^{2x}+1); saturates correctly for |x| large (inf -> 1)
    float e = __expf(2.f * x);
    return 1.f - 2.f * __builtin_amdgcn_rcpf(e + 1.f);
}

// ---------------------------------------------------------------------------
// Kernel 1 (fused): blocks [0, PRE_BLOCKS): wave-per-position attention
//                   blocks [PRE_BLOCKS, +WCONV_BLOCKS): W_out transpose->bf16
// ---------------------------------------------------------------------------
__global__ __launch_bounds__(256)
void pre_kernel(const float* __restrict__ inputs,
                const float* __restrict__ values,
                const float* __restrict__ W,
                const float* __restrict__ w_score,
                const float* __restrict__ b_score,
                const int*   __restrict__ n_ptr,
                __hip_bfloat16* __restrict__ cat,
                float* __restrict__ gate,
                __hip_bfloat16* __restrict__ Wt)
{
    __shared__ float ws[64][65];   // only used by the wconv path (16.6 KB)

    const int tid  = threadIdx.x;

    if (blockIdx.x >= PRE_BLOCKS) {
        // ---- W_out [1024,512] f32 -> Wt [512,1024] bf16, 64x64 LDS tile ----
        const int t  = blockIdx.x - PRE_BLOCKS;
        const int k0 = (t & 15) * 64;     // row tile in W (K dim)
        const int n0 = (t >> 4) * 64;     // col tile in W (N dim)
        #pragma unroll
        for (int i = 0; i < 16; ++i) {
            int e = i * 256 + tid;
            int r = e >> 6, c = e & 63;
            ws[r][c] = W[(size_t)(k0 + r) * N_TOTAL + n0 + c];
        }
        __syncthreads();
        #pragma unroll
        for (int i = 0; i < 16; ++i) {
            int e = i * 256 + tid;
            int nr = e >> 6, kc = e & 63;
            Wt[(size_t)(n0 + nr) * K_TOTAL + k0 + kc] = __float2bfloat16(ws[kc][nr]);
        }
        return;
    }

    // ---- wave-per-position attention: no LDS, no barriers ----
    const int lane = tid & 63;
    const int wv   = tid >> 6;
    const int p    = blockIdx.x * 4 + wv;

    const float4* qg = (const float4*)(inputs + (size_t)p * DIM);
    float4 qa = qg[lane], qb = qg[lane + 64];

    const float4* vg = (const float4*)(values + (size_t)p * (FDIM*DIM));
    float4 ma[4], mb[4];
    float s[4];
    #pragma unroll
    for (int f = 0; f < 4; ++f) {
        ma[f] = vg[f * 128 + lane];
        mb[f] = vg[f * 128 + lane + 64];
        s[f] = dot4(qa, ma[f]) + dot4(qb, mb[f]);
    }
    const float4* wg = (const float4*)w_score;
    float g = dot4(qa, wg[lane]) + dot4(qb, wg[lane + 64]);

    // butterfly reduce the 4 scores + gate across the wave
    #pragma unroll
    for (int off = 1; off < 64; off <<= 1) {
        s[0] += __shfl_xor(s[0], off, 64);
        s[1] += __shfl_xor(s[1], off, 64);
        s[2] += __shfl_xor(s[2], off, 64);
        s[3] += __shfl_xor(s[3], off, 64);
        g    += __shfl_xor(g,    off, 64);
    }

    const int nv = *n_ptr;
    #pragma unroll
    for (int f = 0; f < 4; ++f) if (f >= nv) s[f] = -1e9f;
    float mx = fmaxf(fmaxf(s[0], s[1]), fmaxf(s[2], s[3]));
    float e0 = __expf(s[0] - mx), e1 = __expf(s[1] - mx);
    float e2 = __expf(s[2] - mx), e3 = __expf(s[3] - mx);
    float inv = __builtin_amdgcn_rcpf(e0 + e1 + e2 + e3);
    float a[4] = { e0 * inv, e1 * inv, e2 * inv, e3 * inv };

    float4 ca = {0.f, 0.f, 0.f, 0.f}, cb = {0.f, 0.f, 0.f, 0.f};
    #pragma unroll
    for (int f = 0; f < 4; ++f) {
        ca.x += a[f] * ma[f].x; ca.y += a[f] * ma[f].y;
        ca.z += a[f] * ma[f].z; ca.w += a[f] * ma[f].w;
        cb.x += a[f] * mb[f].x; cb.y += a[f] * mb[f].y;
        cb.z += a[f] * mb[f].z; cb.w += a[f] * mb[f].w;
    }

    __hip_bfloat16* cp = cat + (size_t)p * K_TOTAL;
    store_bf4(cp +        4 * lane, ca);
    store_bf4(cp + 256  + 4 * lane, cb);
    store_bf4(cp + 512  + 4 * lane, qa);
    store_bf4(cp + 768  + 4 * lane, qb);

    if (lane == 0) {
        float t = g + b_score[0];
        gate[p] = __builtin_amdgcn_rcpf(1.f + __expf(-t));
    }
}

// ---------------------------------------------------------------------------
// Kernel 2: out = tanh(cat @ W_out) * gate + inputs
// bf16 MFMA GEMM, BM=BN=128, BK=64, 4 waves (2x2), 4x4 16x16 frags per wave.
// A = cat [M,1024] row-major bf16; Bt = Wt [N,1024] row-major bf16 (B^T).
// LDS staging: linear dest (global_load_lds) + XOR-swizzled GLOBAL source;
// ds_read applies the same XOR -> 2-way banks (free).
// ---------------------------------------------------------------------------
__global__ __launch_bounds__(256)
void gemm_ep(const __hip_bfloat16* __restrict__ A,
             const __hip_bfloat16* __restrict__ Bt,
             const float* __restrict__ gate,
             const float* __restrict__ inputs,
             float* __restrict__ out)
{
    __shared__ __align__(16) __hip_bfloat16 As[128 * 64];  // 16 KB
    __shared__ __align__(16) __hip_bfloat16 Bs[128 * 64];  // 16 KB

    const int tid  = threadIdx.x;
    const int bm   = blockIdx.x;
    const int bn   = blockIdx.y;
    const int wid  = tid >> 6;
    const int lane = tid & 63;
    const int wr   = wid >> 1;       // wave row 0..1
    const int wc   = wid & 1;        // wave col 0..1
    const int la   = lane & 15;
    const int lb   = lane >> 4;

    const int K = K_TOTAL;
    const __hip_bfloat16* Ag = A  + (size_t)(bm * 128) * K;
    const __hip_bfloat16* Bg = Bt + (size_t)(bn * 128) * K;

    f32x4 acc[4][4] = {};

    for (int kt = 0; kt < K; kt += 64) {
        __syncthreads();
        // stage 128x64 of A and B: 4 passes x 256 threads x 16B each.
        // LDS dest linear; global source chunk XOR'd with (row&7).
        #pragma unroll
        for (int ps = 0; ps < 4; ++ps) {
            int cl  = ps * 256 + tid;        // linear 16B-chunk index
            int row = cl >> 3;               // 8 chunks per 64-elem row
            int c   = cl & 7;
            int sc_ = c ^ (row & 7);
            gload_lds16(Ag + (size_t)row * K + kt + sc_ * 8, As + cl * 8);
            gload_lds16(Bg + (size_t)row * K + kt + sc_ * 8, Bs + cl * 8);
        }
        __syncthreads();   // compiler emits vmcnt(0) drain before barrier

        #pragma unroll
        for (int kk = 0; kk < 2; ++kk) {
            bf16x8 af[4], bfv[4];
            #pragma unroll
            for (int i = 0; i < 4; ++i) {
                int row = wr * 64 + i * 16 + la;
                int c   = (kk * 4 + lb) ^ (row & 7);
                af[i] = *reinterpret_cast<const bf16x8*>(As + row * 64 + c * 8);
            }
            #pragma unroll
            for (int j = 0; j < 4; ++j) {
                int row = wc * 64 + j * 16 + la;
                int c   = (kk * 4 + lb) ^ (row & 7);
                bfv[j] = *reinterpret_cast<const bf16x8*>(Bs + row * 64 + c * 8);
            }
            #pragma unroll
            for (int i = 0; i < 4; ++i)
                #pragma unroll
                for (int j = 0; j < 4; ++j)
                    acc[i][j] = __builtin_amdgcn_mfma_f32_16x16x32_bf16(af[i], bfv[j], acc[i][j], 0, 0, 0);
        }
    }

    // Epilogue: C/D mapping col = lane&15, row = (lane>>4)*4 + reg  [m89/m91]
    const int row0 = bm * 128 + wr * 64;
    const int col0 = bn * 128 + wc * 64;
    #pragma unroll
    for (int i = 0; i < 4; ++i) {
        #pragma unroll
        for (int j = 0; j < 4; ++j) {
            const int col = col0 + j * 16 + la;
            const int rb  = row0 + i * 16 + lb * 4;
            #pragma unroll
            for (int r = 0; r < 4; ++r) {
                const int row = rb + r;
                float v = fast_tanh(acc[i][j][r]) * gate[row] + inputs[(size_t)row * DIM + col];
                out[(size_t)row * DIM + col] = v;
            }
        }
    }
}

// ---------------------------------------------------------------------------
extern "C" void kernel_launch(void* const* d_in, const int* in_sizes, int n_in,
                              void* d_out, int out_size, void* d_ws, size_t ws_size,
                              hipStream_t stream) {
    const float* inputs  = (const float*)d_in[0];
    const float* values  = (const float*)d_in[1];
    const float* W_out   = (const float*)d_in[2];
    const float* w_score = (const float*)d_in[3];
    const float* b_score = (const float*)d_in[4];
    const int*   n_ptr   = (const int*)d_in[5];
    float* out = (float*)d_out;

    char* ws = (char*)d_ws;
    __hip_bfloat16* cat  = (__hip_bfloat16*)ws;                                   // 64 MiB
    float*          gate = (float*)(ws + (size_t)M_TOTAL * K_TOTAL * 2);          // 128 KiB
    __hip_bfloat16* Wt   = (__hip_bfloat16*)(ws + (size_t)M_TOTAL * K_TOTAL * 2
                                                + (size_t)M_TOTAL * 4);           // 1 MiB

    pre_kernel<<<PRE_BLOCKS + WCONV_BLOCKS, 256, 0, stream>>>(
        inputs, values, W_out, w_score, b_score, n_ptr, cat, gate, Wt);
    dim3 g3(M_TOTAL / 128, N_TOTAL / 128);
    gemm_ep<<<g3, 256, 0, stream>>>(cat, Wt, gate, inputs, out);
}

// Round 4
// 126.888 us; speedup vs baseline: 1.4990x; 1.0662x over previous
//
#include <hip/hip_runtime.h>
#include <hip/hip_bf16.h>
#include <math.h>

// Problem constants (fixed by setup_inputs)
#define BATCH 8
#define SEQ   4096
#define DIM   512        // D
#define FDIM  4          // F
#define M_TOTAL (BATCH*SEQ)   // 32768 positions
#define K_TOTAL (2*DIM)       // 1024 (cat = [ctx; q])
#define N_TOTAL DIM           // 512

#define PRE_BLOCKS (M_TOTAL/4)          // 8192 blocks, 4 positions (waves) each
#define WCONV_BLOCKS ((K_TOTAL/64)*(N_TOTAL/64))  // 16*8 = 128 tiles

typedef __bf16 bf16x8 __attribute__((ext_vector_type(8)));
typedef float  f32x4  __attribute__((ext_vector_type(4)));

__device__ __forceinline__ void gload_lds16(const void* g, void* l) {
    __builtin_amdgcn_global_load_lds(
        (__attribute__((address_space(1))) void*)(void*)g,
        (__attribute__((address_space(3))) void*)l,
        16, 0, 0);
}

__device__ __forceinline__ float dot4(float4 a, float4 b) {
    return a.x*b.x + a.y*b.y + a.z*b.z + a.w*b.w;
}

__device__ __forceinline__ void store_bf4(__hip_bfloat16* dst, float4 v) {
    __hip_bfloat16 t[4];
    t[0] = __float2bfloat16(v.x); t[1] = __float2bfloat16(v.y);
    t[2] = __float2bfloat16(v.z); t[3] = __float2bfloat16(v.w);
    *reinterpret_cast<uint2*>(dst) = *reinterpret_cast<const uint2*>(t);
}

__device__ __forceinline__ float fast_tanh(float x) {
    // tanh(x) = 1 - 2/(e^{2x}+1); saturates correctly for |x| large (inf -> 1)
    float e = __expf(2.f * x);
    return 1.f - 2.f * __builtin_amdgcn_rcpf(e + 1.f);
}

// ---------------------------------------------------------------------------
// Kernel 1 (fused): blocks [0, PRE_BLOCKS): wave-per-position attention
//                   blocks [PRE_BLOCKS, +WCONV_BLOCKS): W_out transpose->bf16
// Writes ONLY ctx (bf16, [M,512]) — the q half of cat is staged by the GEMM
// directly from inputs.
// ---------------------------------------------------------------------------
__global__ __launch_bounds__(256)
void pre_kernel(const float* __restrict__ inputs,
                const float* __restrict__ values,
                const float* __restrict__ W,
                const float* __restrict__ w_score,
                const float* __restrict__ b_score,
                const int*   __restrict__ n_ptr,
                __hip_bfloat16* __restrict__ ctx,
                float* __restrict__ gate,
                __hip_bfloat16* __restrict__ Wt)
{
    __shared__ float ws[64][65];   // only used by the wconv path (16.6 KB)

    const int tid  = threadIdx.x;

    if (blockIdx.x >= PRE_BLOCKS) {
        // ---- W_out [1024,512] f32 -> Wt [512,1024] bf16, 64x64 LDS tile ----
        const int t  = blockIdx.x - PRE_BLOCKS;
        const int k0 = (t & 15) * 64;     // row tile in W (K dim)
        const int n0 = (t >> 4) * 64;     // col tile in W (N dim)
        #pragma unroll
        for (int i = 0; i < 16; ++i) {
            int e = i * 256 + tid;
            int r = e >> 6, c = e & 63;
            ws[r][c] = W[(size_t)(k0 + r) * N_TOTAL + n0 + c];
        }
        __syncthreads();
        #pragma unroll
        for (int i = 0; i < 16; ++i) {
            int e = i * 256 + tid;
            int nr = e >> 6, kc = e & 63;
            Wt[(size_t)(n0 + nr) * K_TOTAL + k0 + kc] = __float2bfloat16(ws[kc][nr]);
        }
        return;
    }

    // ---- wave-per-position attention: no LDS, no barriers ----
    const int lane = tid & 63;
    const int wv   = tid >> 6;
    const int p    = blockIdx.x * 4 + wv;

    const float4* qg = (const float4*)(inputs + (size_t)p * DIM);
    float4 qa = qg[lane], qb = qg[lane + 64];

    const float4* vg = (const float4*)(values + (size_t)p * (FDIM*DIM));
    float4 ma[4], mb[4];
    float s[4];
    #pragma unroll
    for (int f = 0; f < 4; ++f) {
        ma[f] = vg[f * 128 + lane];
        mb[f] = vg[f * 128 + lane + 64];
        s[f] = dot4(qa, ma[f]) + dot4(qb, mb[f]);
    }
    const float4* wg = (const float4*)w_score;
    float g = dot4(qa, wg[lane]) + dot4(qb, wg[lane + 64]);

    // butterfly reduce the 4 scores + gate across the wave
    #pragma unroll
    for (int off = 1; off < 64; off <<= 1) {
        s[0] += __shfl_xor(s[0], off, 64);
        s[1] += __shfl_xor(s[1], off, 64);
        s[2] += __shfl_xor(s[2], off, 64);
        s[3] += __shfl_xor(s[3], off, 64);
        g    += __shfl_xor(g,    off, 64);
    }

    const int nv = *n_ptr;
    #pragma unroll
    for (int f = 0; f < 4; ++f) if (f >= nv) s[f] = -1e9f;
    float mx = fmaxf(fmaxf(s[0], s[1]), fmaxf(s[2], s[3]));
    float e0 = __expf(s[0] - mx), e1 = __expf(s[1] - mx);
    float e2 = __expf(s[2] - mx), e3 = __expf(s[3] - mx);
    float inv = __builtin_amdgcn_rcpf(e0 + e1 + e2 + e3);
    float a[4] = { e0 * inv, e1 * inv, e2 * inv, e3 * inv };

    float4 ca = {0.f, 0.f, 0.f, 0.f}, cb = {0.f, 0.f, 0.f, 0.f};
    #pragma unroll
    for (int f = 0; f < 4; ++f) {
        ca.x += a[f] * ma[f].x; ca.y += a[f] * ma[f].y;
        ca.z += a[f] * ma[f].z; ca.w += a[f] * ma[f].w;
        cb.x += a[f] * mb[f].x; cb.y += a[f] * mb[f].y;
        cb.z += a[f] * mb[f].z; cb.w += a[f] * mb[f].w;
    }

    __hip_bfloat16* cp = ctx + (size_t)p * DIM;
    store_bf4(cp +        4 * lane, ca);
    store_bf4(cp + 256  + 4 * lane, cb);

    if (lane == 0) {
        float t = g + b_score[0];
        gate[p] = __builtin_amdgcn_rcpf(1.f + __expf(-t));
    }
}

// ---------------------------------------------------------------------------
// Kernel 2: out = tanh([ctx; q] @ W_out) * gate + inputs
// bf16 MFMA GEMM, BM=BN=128, BK=64, 4 waves (2x2), 4x4 16x16 frags per wave.
// K-split: kt<512 -> A from ctx bf16 (global_load_lds, swizzled source);
//          kt>=512 -> A reg-staged from inputs f32 (cvt->ds_write, swizzled src).
// Bt = Wt [N,1024] row-major bf16 (B^T), always global_load_lds.
// __launch_bounds__(256,4): cap 128 VGPR -> 4 blocks/CU -> grid of 1024 runs
// in exactly one residency round (no tail).
// ---------------------------------------------------------------------------
__global__ __launch_bounds__(256, 4)
void gemm_ep(const __hip_bfloat16* __restrict__ Actx,
             const __hip_bfloat16* __restrict__ Bt,
             const float* __restrict__ gate,
             const float* __restrict__ inputs,
             float* __restrict__ out)
{
    __shared__ __align__(16) __hip_bfloat16 As[128 * 64];  // 16 KB
    __shared__ __align__(16) __hip_bfloat16 Bs[128 * 64];  // 16 KB

    const int tid  = threadIdx.x;
    const int bm   = blockIdx.x;
    const int bn   = blockIdx.y;
    const int wid  = tid >> 6;
    const int lane = tid & 63;
    const int wr   = wid >> 1;       // wave row 0..1
    const int wc   = wid & 1;        // wave col 0..1
    const int la   = lane & 15;
    const int lb   = lane >> 4;

    const __hip_bfloat16* Ag = Actx + (size_t)(bm * 128) * DIM;       // stride 512
    const float*          Qg = inputs + (size_t)(bm * 128) * DIM;     // stride 512
    const __hip_bfloat16* Bg = Bt + (size_t)(bn * 128) * K_TOTAL;     // stride 1024

    f32x4 acc[4][4] = {};

    for (int kt = 0; kt < K_TOTAL; kt += 64) {
        __syncthreads();
        // stage 128x64 of A and B: 4 passes x 256 threads x 16B each.
        // LDS dest linear; source chunk XOR'd with (row&7) (matches read).
        if (kt < 512) {
            #pragma unroll
            for (int ps = 0; ps < 4; ++ps) {
                int cl  = ps * 256 + tid;        // linear 16B-chunk index
                int row = cl >> 3;               // 8 chunks per 64-elem row
                int c   = cl & 7;
                int sc_ = c ^ (row & 7);
                gload_lds16(Ag + (size_t)row * DIM + kt + sc_ * 8, As + cl * 8);
                gload_lds16(Bg + (size_t)row * K_TOTAL + kt + sc_ * 8, Bs + cl * 8);
            }
        } else {
            #pragma unroll
            for (int ps = 0; ps < 4; ++ps) {
                int cl  = ps * 256 + tid;
                int row = cl >> 3;
                int c   = cl & 7;
                int sc_ = c ^ (row & 7);
                gload_lds16(Bg + (size_t)row * K_TOTAL + kt + sc_ * 8, Bs + cl * 8);
                // A q-half: f32 -> bf16 reg-staged
                const float* src = Qg + (size_t)row * DIM + (kt - 512) + sc_ * 8;
                float4 f0 = ((const float4*)src)[0];
                float4 f1 = ((const float4*)src)[1];
                __hip_bfloat16 t[8];
                t[0] = __float2bfloat16(f0.x); t[1] = __float2bfloat16(f0.y);
                t[2] = __float2bfloat16(f0.z); t[3] = __float2bfloat16(f0.w);
                t[4] = __float2bfloat16(f1.x); t[5] = __float2bfloat16(f1.y);
                t[6] = __float2bfloat16(f1.z); t[7] = __float2bfloat16(f1.w);
                *reinterpret_cast<uint4*>(As + cl * 8) = *reinterpret_cast<const uint4*>(t);
            }
        }
        __syncthreads();   // compiler emits vmcnt/lgkm drain before barrier

        #pragma unroll
        for (int kk = 0; kk < 2; ++kk) {
            bf16x8 af[4], bfv[4];
            #pragma unroll
            for (int i = 0; i < 4; ++i) {
                int row = wr * 64 + i * 16 + la;
                int c   = (kk * 4 + lb) ^ (row & 7);
                af[i] = *reinterpret_cast<const bf16x8*>(As + row * 64 + c * 8);
            }
            #pragma unroll
            for (int j = 0; j < 4; ++j) {
                int row = wc * 64 + j * 16 + la;
                int c   = (kk * 4 + lb) ^ (row & 7);
                bfv[j] = *reinterpret_cast<const bf16x8*>(Bs + row * 64 + c * 8);
            }
            #pragma unroll
            for (int i = 0; i < 4; ++i)
                #pragma unroll
                for (int j = 0; j < 4; ++j)
                    acc[i][j] = __builtin_amdgcn_mfma_f32_16x16x32_bf16(af[i], bfv[j], acc[i][j], 0, 0, 0);
        }
    }

    // Epilogue: C/D mapping col = lane&15, row = (lane>>4)*4 + reg  [m89/m91]
    const int row0 = bm * 128 + wr * 64;
    const int col0 = bn * 128 + wc * 64;
    #pragma unroll
    for (int i = 0; i < 4; ++i) {
        #pragma unroll
        for (int j = 0; j < 4; ++j) {
            const int col = col0 + j * 16 + la;
            const int rb  = row0 + i * 16 + lb * 4;
            #pragma unroll
            for (int r = 0; r < 4; ++r) {
                const int row = rb + r;
                float v = fast_tanh(acc[i][j][r]) * gate[row] + inputs[(size_t)row * DIM + col];
                out[(size_t)row * DIM + col] = v;
            }
        }
    }
}

// ---------------------------------------------------------------------------
extern "C" void kernel_launch(void* const* d_in, const int* in_sizes, int n_in,
                              void* d_out, int out_size, void* d_ws, size_t ws_size,
                              hipStream_t stream) {
    const float* inputs  = (const float*)d_in[0];
    const float* values  = (const float*)d_in[1];
    const float* W_out   = (const float*)d_in[2];
    const float* w_score = (const float*)d_in[3];
    const float* b_score = (const float*)d_in[4];
    const int*   n_ptr   = (const int*)d_in[5];
    float* out = (float*)d_out;

    char* ws = (char*)d_ws;
    __hip_bfloat16* ctx  = (__hip_bfloat16*)ws;                                   // 32 MiB
    float*          gate = (float*)(ws + (size_t)M_TOTAL * DIM * 2);              // 128 KiB
    __hip_bfloat16* Wt   = (__hip_bfloat16*)(ws + (size_t)M_TOTAL * DIM * 2
                                                + (size_t)M_TOTAL * 4);           // 1 MiB

    pre_kernel<<<PRE_BLOCKS + WCONV_BLOCKS, 256, 0, stream>>>(
        inputs, values, W_out, w_score, b_score, n_ptr, ctx, gate, Wt);
    dim3 g3(M_TOTAL / 128, N_TOTAL / 128);
    gemm_ep<<<g3, 256, 0, stream>>>(ctx, Wt, gate, inputs, out);
}